// Round 11
// baseline (277.407 us; speedup 1.0000x reference)
//
#include <hip/hip_runtime.h>

// GINE 2-layer GNN: N=50000 nodes, E=800000 edges, d=128.
// Round 11 (= round 10 + compile fix): __builtin_nontemporal_store needs a
// clang-native vector type, not HIP's uint4 class -> use ext_vector_type(4).
//  - colscan + scanS folded into bucket_scatter (9 -> 7 dispatches).
//  - aggregate: 16 lanes/node x 16B loads (8 bf16) -> half the load
//    instructions + address VALU per edge, same bytes, 12500 waves, 8-deep.
// bf16 feature path, f32 accumulation (absmax 4.0 vs threshold 15.04).

typedef unsigned long long u64;
typedef unsigned int u32;
typedef unsigned short ushort;
typedef __attribute__((ext_vector_type(8))) short short8;
typedef __attribute__((ext_vector_type(4))) float f32x4;
typedef __attribute__((ext_vector_type(4))) u32 u32x4;   // native vec for NT ops

constexpr int NN = 50000;
constexpr int NE = 800000;
constexpr int D  = 128;
constexpr int BSH = 6;                    // 64 nodes per bucket
constexpr int NB  = (NN + 63) >> BSH;     // 782 buckets
constexpr int NC  = 128;                  // edge chunks
constexpr int CHUNK = NE / NC;            // 6250
constexpr int BCAP = 4096;
constexpr int GR = 64;                    // GEMM rows per block
constexpr int GG = (NN + GR - 1) / GR;    // 782
constexpr int CBLK = NN * D / 8 / 256;    // 3125 cast blocks (exact)

__device__ __forceinline__ ushort f2bf(float f) {
    u32 u = __float_as_uint(f);
    return (ushort)((u + 0x7FFFu + ((u >> 16) & 1u)) >> 16);
}
__device__ __forceinline__ float bfl(u32 u) {            // low bf16 -> f32
    return __uint_as_float(u << 16);
}
__device__ __forceinline__ float bfh(u32 u) {            // high bf16 -> f32
    return __uint_as_float(u & 0xFFFF0000u);
}
__device__ __forceinline__ u64 pack_edge(int src, int d6, float w) {
    return ((u64)__float_as_uint(w) << 32) | (u32)(src | (d6 << 17));
}

// ---- prep+hist: cast x -> bf16, transpose+cast W1/W2, dst histogram ----

__global__ __launch_bounds__(256) void prep_hist(
    const float* __restrict__ x,  ushort* __restrict__ xb,
    const float* __restrict__ W1, const float* __restrict__ W2,
    ushort* __restrict__ Wt1, ushort* __restrict__ Wt2,
    const int* __restrict__ dst, int* __restrict__ G)
{
    int blk = blockIdx.x;
    if (blk < CBLK) {
        int base = (blk * 256 + threadIdx.x) * 8;
        float4 a = *(const float4*)(x + base);
        float4 b = *(const float4*)(x + base + 4);
        uint4 o;
        o.x = (u32)f2bf(a.x) | ((u32)f2bf(a.y) << 16);
        o.y = (u32)f2bf(a.z) | ((u32)f2bf(a.w) << 16);
        o.z = (u32)f2bf(b.x) | ((u32)f2bf(b.y) << 16);
        o.w = (u32)f2bf(b.z) | ((u32)f2bf(b.w) << 16);
        *(uint4*)(xb + base) = o;
    } else if (blk < CBLK + 8) {
        int b = blk - CBLK;                 // 0..7
        const float* W  = (b >= 4) ? W2 : W1;
        ushort*      Wt = (b >= 4) ? Wt2 : Wt1;
        int k0 = (b & 3) * 32;
        for (int i = threadIdx.x; i < 32 * D; i += 256) {
            int n = i >> 5, r = i & 31;
            Wt[n * D + k0 + r] = f2bf(W[(k0 + r) * D + n]);
        }
    } else {
        __shared__ int hh[NB];
        int t = threadIdx.x, c = blk - CBLK - 8;
        for (int i = t; i < NB; i += 256) hh[i] = 0;
        __syncthreads();
        int e0 = c * CHUNK;
        for (int i = t; i < CHUNK; i += 256)
            atomicAdd(&hh[dst[e0 + i] >> BSH], 1);
        __syncthreads();
        for (int i = t; i < NB; i += 256) G[c * NB + i] = hh[i];
    }
}

// ---- bucket_scatter with in-kernel column-scan (replaces colscan+scanS) ----

__global__ __launch_bounds__(256) void bucket_scatter(
    const int*   __restrict__ src,
    const int*   __restrict__ dst,
    const float* __restrict__ ew,
    const int*   __restrict__ G,
    int*         __restrict__ B,
    u64*         __restrict__ stage)
{
    __shared__ int sum_s[NB];
    __shared__ int pre_s[NB];
    __shared__ int base_s[NB];
    __shared__ int cnt_s[NB];
    __shared__ int tsum[256];
    const int t = threadIdx.x, c = blockIdx.x;

    // phase A: bucket totals S and my column prefix P (over chunks < c)
    for (int b = t; b < NB; b += 256) {
        int S = 0, P = 0;
        #pragma unroll 8
        for (int cc = 0; cc < NC; ++cc) {
            int g = G[cc * NB + b];
            S += g;
            if (cc < c) P += g;
        }
        sum_s[b] = S;
        pre_s[b] = P;
    }
    __syncthreads();

    // phase B: exclusive scan of sum_s -> base_s
    {
        int o0 = t * 4;      // 256*4 = 1024 >= NB
        int l0 = (o0 + 0 < NB) ? sum_s[o0 + 0] : 0;
        int l1 = (o0 + 1 < NB) ? sum_s[o0 + 1] : 0;
        int l2 = (o0 + 2 < NB) ? sum_s[o0 + 2] : 0;
        int l3 = (o0 + 3 < NB) ? sum_s[o0 + 3] : 0;
        int s = l0 + l1 + l2 + l3;
        tsum[t] = s;
        __syncthreads();
        for (int d = 1; d < 256; d <<= 1) {
            int v = (t >= d) ? tsum[t - d] : 0;
            __syncthreads();
            tsum[t] += v;
            __syncthreads();
        }
        int run = tsum[t] - s;
        if (o0 + 0 < NB) base_s[o0 + 0] = run;  run += l0;
        if (o0 + 1 < NB) base_s[o0 + 1] = run;  run += l1;
        if (o0 + 2 < NB) base_s[o0 + 2] = run;  run += l2;
        if (o0 + 3 < NB) base_s[o0 + 3] = run;
    }
    __syncthreads();

    if (c == 0) {                          // publish B for bucket_csr
        for (int b = t; b < NB; b += 256) B[b] = base_s[b];
        if (t == 0) B[NB] = NE;
    }
    for (int b = t; b < NB; b += 256) {
        base_s[b] += pre_s[b];
        cnt_s[b] = 0;
    }
    __syncthreads();

    // phase C: scatter my chunk
    int e0 = c * CHUNK;
    for (int i = t; i < CHUNK; i += 256) {
        int e  = e0 + i;
        int d  = dst[e];
        int bk = d >> BSH;
        int r  = atomicAdd(&cnt_s[bk], 1);
        stage[base_s[bk] + r] = pack_edge(src[e], d & 63, ew[e]);
    }
}

// per bucket: counting sort by node, contiguous writeback, per-node offsets.
__global__ __launch_bounds__(256) void bucket_csr(
    const int* __restrict__ B, u64* __restrict__ stage, int* __restrict__ off)
{
    __shared__ u64 buf[BCAP];           // 32 KB
    __shared__ int cnt[64];
    __shared__ int cur[64];
    __shared__ int noff[64];
    int t = threadIdx.x, b = blockIdx.x;
    int e0 = B[b], e1 = B[b + 1];
    int n = e1 - e0;
    if (n > BCAP) n = BCAP;
    if (t < 64) { cnt[t] = 0; cur[t] = 0; }
    __syncthreads();
    for (int i = t; i < n; i += 256)
        atomicAdd(&cnt[(int)((stage[e0 + i] >> 17) & 63)], 1);
    __syncthreads();
    if (t == 0) {
        int run = 0;
        for (int j = 0; j < 64; ++j) { noff[j] = run; run += cnt[j]; }
    }
    __syncthreads();
    int n0 = b << BSH;
    if (t < 64 && (n0 + t) < NN) off[n0 + t] = e0 + noff[t];
    if (b == NB - 1 && t == 0) off[NN] = NE;
    for (int i = t; i < n; i += 256) {
        u64 p = stage[e0 + i];
        int d6 = (int)((p >> 17) & 63);
        int r = atomicAdd(&cur[d6], 1);
        buf[noff[d6] + r] = p;
    }
    __syncthreads();
    for (int i = t; i < n; i += 256) stage[e0 + i] = buf[i];
}

// ---- per-layer aggregate: 16 lanes/node x 16B loads (8 bf16), 8-deep ------

__global__ __launch_bounds__(256) void aggregate(
    const ushort* __restrict__ hb,
    const int*    __restrict__ off,
    const u64*    __restrict__ epk,
    const float*  __restrict__ We,
    const float*  __restrict__ be,
    ushort*       __restrict__ aggb)
{
    int tid = blockIdx.x * 256 + threadIdx.x;
    int n = tid >> 4;
    if (n >= NN) return;
    int d8 = (tid & 15) << 3;

    float4 wv0 = *(const float4*)(We + d8);
    float4 wv1 = *(const float4*)(We + d8 + 4);
    float4 bv0 = *(const float4*)(be + d8);
    float4 bv1 = *(const float4*)(be + d8 + 4);

    int e0 = off[n], e1 = off[n + 1];
    float a0=0.f,a1=0.f,a2=0.f,a3=0.f,a4=0.f,a5=0.f,a6=0.f,a7=0.f;

    for (int e = e0; e < e1; e += 8) {
        int m = e1 - e; if (m > 8) m = 8;
        u64 p[8];
        #pragma unroll
        for (int k = 0; k < 8; ++k) p[k] = (k < m) ? epk[e + k] : 0;
        u32x4 hv[8];
        #pragma unroll
        for (int k = 0; k < 8; ++k)
            hv[k] = *(const u32x4*)(hb + (size_t)(p[k] & 0x1FFFF) * D + d8);
        #pragma unroll
        for (int k = 0; k < 8; ++k) {
            if (k < m) {
                float w = __uint_as_float((u32)(p[k] >> 32));
                a0 += fmaxf(0.f, bfl(hv[k].x) + fmaf(w, wv0.x, bv0.x));
                a1 += fmaxf(0.f, bfh(hv[k].x) + fmaf(w, wv0.y, bv0.y));
                a2 += fmaxf(0.f, bfl(hv[k].y) + fmaf(w, wv0.z, bv0.z));
                a3 += fmaxf(0.f, bfh(hv[k].y) + fmaf(w, wv0.w, bv0.w));
                a4 += fmaxf(0.f, bfl(hv[k].z) + fmaf(w, wv1.x, bv1.x));
                a5 += fmaxf(0.f, bfh(hv[k].z) + fmaf(w, wv1.y, bv1.y));
                a6 += fmaxf(0.f, bfl(hv[k].w) + fmaf(w, wv1.z, bv1.z));
                a7 += fmaxf(0.f, bfh(hv[k].w) + fmaf(w, wv1.w, bv1.w));
            }
        }
    }
    u32x4 o;
    o.x = (u32)f2bf(a0) | ((u32)f2bf(a1) << 16);
    o.y = (u32)f2bf(a2) | ((u32)f2bf(a3) << 16);
    o.z = (u32)f2bf(a4) | ((u32)f2bf(a5) << 16);
    o.w = (u32)f2bf(a6) | ((u32)f2bf(a7) << 16);
    __builtin_nontemporal_store(o, (u32x4*)(aggb + (size_t)n * D + d8));
}

// ---------- MFMA GEMM: out = (relu?)((A1+A2) @ W + bias) ----------

__global__ __launch_bounds__(256) void gemm_mfma(
    const ushort* __restrict__ A1b,
    const ushort* __restrict__ A2b,   // aggb (streamed, read-once)
    const ushort* __restrict__ Wtb,
    const float*  __restrict__ bias,
    float*        __restrict__ outf,   // layer 2 (or null)
    ushort*       __restrict__ outb,   // layer 1 (or null)
    int relu)
{
    __shared__ ushort As[GR * 140];
    __shared__ ushort Ws[D * 140];

    const int t    = threadIdx.x;
    const int row0 = blockIdx.x * GR;

    for (int c = t; c < GR * (D / 4); c += 256) {
        int r  = c >> 5;
        int k4 = (c & 31) << 2;
        int row = row0 + r;
        uint2 o = make_uint2(0u, 0u);
        if (row < NN) {
            uint2 u1 = *(const uint2*)(A1b + (size_t)row * D + k4);
            u64 uu = __builtin_nontemporal_load((const u64*)(A2b + (size_t)row * D + k4));
            uint2 u2 = make_uint2((u32)uu, (u32)(uu >> 32));
            float s0 = bfl(u1.x) + bfl(u2.x);
            float s1 = bfh(u1.x) + bfh(u2.x);
            float s2 = bfl(u1.y) + bfl(u2.y);
            float s3 = bfh(u1.y) + bfh(u2.y);
            o.x = (u32)f2bf(s0) | ((u32)f2bf(s1) << 16);
            o.y = (u32)f2bf(s2) | ((u32)f2bf(s3) << 16);
        }
        *(uint2*)&As[r * 140 + k4] = o;
    }
    for (int c = t; c < D * (D / 4); c += 256) {
        int r  = c >> 5;
        int k4 = (c & 31) << 2;
        *(uint2*)&Ws[r * 140 + k4] = *(const uint2*)(Wtb + r * D + k4);
    }
    __syncthreads();

    const int wave = t >> 6;
    const int lane = t & 63;
    const int q    = lane >> 4;
    const int m    = lane & 15;
    const int wr   = (wave >> 1) * 32;
    const int wc   = (wave & 1) * 64;

    f32x4 acc[2][4] = {};
    #pragma unroll
    for (int kb = 0; kb < 4; ++kb) {
        int ak = kb * 32 + q * 8;
        short8 af[2];
        #pragma unroll
        for (int rg = 0; rg < 2; ++rg)
            af[rg] = *(const short8*)&As[(wr + rg * 16 + m) * 140 + ak];
        #pragma unroll
        for (int ct = 0; ct < 4; ++ct) {
            short8 bf = *(const short8*)&Ws[(wc + ct * 16 + m) * 140 + ak];
            #pragma unroll
            for (int rg = 0; rg < 2; ++rg)
                acc[rg][ct] = __builtin_amdgcn_mfma_f32_16x16x32_bf16(
                    af[rg], bf, acc[rg][ct], 0, 0, 0);
        }
    }

    #pragma unroll
    for (int ct = 0; ct < 4; ++ct) {
        int col = wc + ct * 16 + m;
        float bc = bias[col];
        #pragma unroll
        for (int rg = 0; rg < 2; ++rg) {
            #pragma unroll
            for (int r = 0; r < 4; ++r) {
                int grow = row0 + wr + rg * 16 + q * 4 + r;
                if (grow < NN) {
                    float v = acc[rg][ct][r] + bc;
                    if (relu) v = fmaxf(0.f, v);
                    if (outb) outb[(size_t)grow * D + col] = f2bf(v);
                    else __builtin_nontemporal_store(v, outf + (size_t)grow * D + col);
                }
            }
        }
    }
}

extern "C" void kernel_launch(void* const* d_in, const int* in_sizes, int n_in,
                              void* d_out, int out_size, void* d_ws, size_t ws_size,
                              hipStream_t stream)
{
    const float* x   = (const float*)d_in[0];
    const int*   ei  = (const int*)  d_in[1];
    const float* ew  = (const float*)d_in[2];
    const float* We1 = (const float*)d_in[3];
    const float* be1 = (const float*)d_in[4];
    const float* W1  = (const float*)d_in[5];
    const float* b1  = (const float*)d_in[6];
    const float* We2 = (const float*)d_in[7];
    const float* be2 = (const float*)d_in[8];
    const float* W2  = (const float*)d_in[9];
    const float* b2  = (const float*)d_in[10];

    float* out = (float*)d_out;

    // workspace (~46 MB)
    ushort* xb   = (ushort*)d_ws;                    // NN*D bf16
    ushort* hb   = xb + (size_t)NN * D;              // NN*D
    ushort* aggb = hb + (size_t)NN * D;              // NN*D
    ushort* Wt1  = aggb + (size_t)NN * D;            // 16384
    ushort* Wt2  = Wt1 + D * D;                      // 16384
    u64*   stage = (u64*)(Wt2 + D * D);              // NE u64
    int*   G     = (int*)(stage + NE);               // NC*NB
    int*   B     = G + NC * NB;                      // NB+1
    int*   off   = B + NB + 2;                       // NN+1

    const int* src = ei;
    const int* dst = ei + NE;

    dim3 agrid((NN * 16 + 255) / 256);               // 3125

    // ---- prep (cast x, transpose W) + hist, one launch ----
    prep_hist<<<CBLK + 8 + NC, 256, 0, stream>>>(x, xb, W1, W2, Wt1, Wt2,
                                                 dst, G);

    // ---- bucket-sorted CSR build (scan folded into scatter) ----
    bucket_scatter<<<NC, 256, 0, stream>>>(src, dst, ew, G, B, stage);
    bucket_csr<<<NB, 256, 0, stream>>>(B, stage, off);

    // ---- layer 1 ----
    aggregate<<<agrid, 256, 0, stream>>>(xb, off, stage, We1, be1, aggb);
    gemm_mfma<<<GG, 256, 0, stream>>>(xb, aggb, Wt1, b1, nullptr, hb, 1);

    // ---- layer 2 ----
    aggregate<<<agrid, 256, 0, stream>>>(hb, off, stage, We2, be2, aggb);
    gemm_mfma<<<GG, 256, 0, stream>>>(hb, aggb, Wt2, b2, out, nullptr, 0);
}

// Round 12
// 249.940 us; speedup vs baseline: 1.1099x; 1.1099x over previous
//
#include <hip/hip_runtime.h>

// GINE 2-layer GNN: N=50000 nodes, E=800000 edges, d=128.
// Round 12: bucket_scatter was 47.6us at 4% occupancy -- 128 blocks x 256
// threads = 2 waves/CU on half the chip; random-store latency unhidden.
// Fix: 1024-thread scatter blocks (same NC=128 chunks -> same 64B run
// coherence, WRITE_SIZE ~11MB), 16 waves/block = 8x the latency hiding.
// Everything else unchanged from round 11.
// bf16 feature path, f32 accumulation (absmax 4.0 vs threshold 15.04).

typedef unsigned long long u64;
typedef unsigned int u32;
typedef unsigned short ushort;
typedef __attribute__((ext_vector_type(8))) short short8;
typedef __attribute__((ext_vector_type(4))) float f32x4;
typedef __attribute__((ext_vector_type(4))) u32 u32x4;   // native vec for NT ops

constexpr int NN = 50000;
constexpr int NE = 800000;
constexpr int D  = 128;
constexpr int BSH = 6;                    // 64 nodes per bucket
constexpr int NB  = (NN + 63) >> BSH;     // 782 buckets
constexpr int NC  = 128;                  // edge chunks
constexpr int CHUNK = NE / NC;            // 6250
constexpr int BCAP = 4096;
constexpr int GR = 64;                    // GEMM rows per block
constexpr int GG = (NN + GR - 1) / GR;    // 782
constexpr int CBLK = NN * D / 8 / 256;    // 3125 cast blocks (exact)

__device__ __forceinline__ ushort f2bf(float f) {
    u32 u = __float_as_uint(f);
    return (ushort)((u + 0x7FFFu + ((u >> 16) & 1u)) >> 16);
}
__device__ __forceinline__ float bfl(u32 u) {            // low bf16 -> f32
    return __uint_as_float(u << 16);
}
__device__ __forceinline__ float bfh(u32 u) {            // high bf16 -> f32
    return __uint_as_float(u & 0xFFFF0000u);
}
__device__ __forceinline__ u64 pack_edge(int src, int d6, float w) {
    return ((u64)__float_as_uint(w) << 32) | (u32)(src | (d6 << 17));
}

// ---- prep+hist: cast x -> bf16, transpose+cast W1/W2, dst histogram ----

__global__ __launch_bounds__(256) void prep_hist(
    const float* __restrict__ x,  ushort* __restrict__ xb,
    const float* __restrict__ W1, const float* __restrict__ W2,
    ushort* __restrict__ Wt1, ushort* __restrict__ Wt2,
    const int* __restrict__ dst, int* __restrict__ G)
{
    int blk = blockIdx.x;
    if (blk < CBLK) {
        int base = (blk * 256 + threadIdx.x) * 8;
        float4 a = *(const float4*)(x + base);
        float4 b = *(const float4*)(x + base + 4);
        uint4 o;
        o.x = (u32)f2bf(a.x) | ((u32)f2bf(a.y) << 16);
        o.y = (u32)f2bf(a.z) | ((u32)f2bf(a.w) << 16);
        o.z = (u32)f2bf(b.x) | ((u32)f2bf(b.y) << 16);
        o.w = (u32)f2bf(b.z) | ((u32)f2bf(b.w) << 16);
        *(uint4*)(xb + base) = o;
    } else if (blk < CBLK + 8) {
        int b = blk - CBLK;                 // 0..7
        const float* W  = (b >= 4) ? W2 : W1;
        ushort*      Wt = (b >= 4) ? Wt2 : Wt1;
        int k0 = (b & 3) * 32;
        for (int i = threadIdx.x; i < 32 * D; i += 256) {
            int n = i >> 5, r = i & 31;
            Wt[n * D + k0 + r] = f2bf(W[(k0 + r) * D + n]);
        }
    } else {
        __shared__ int hh[NB];
        int t = threadIdx.x, c = blk - CBLK - 8;
        for (int i = t; i < NB; i += 256) hh[i] = 0;
        __syncthreads();
        int e0 = c * CHUNK;
        for (int i = t; i < CHUNK; i += 256)
            atomicAdd(&hh[dst[e0 + i] >> BSH], 1);
        __syncthreads();
        for (int i = t; i < NB; i += 256) G[c * NB + i] = hh[i];
    }
}

// ---- bucket_scatter, 1024 threads/block, in-kernel column scan ----

__global__ __launch_bounds__(1024) void bucket_scatter(
    const int*   __restrict__ src,
    const int*   __restrict__ dst,
    const float* __restrict__ ew,
    const int*   __restrict__ G,
    int*         __restrict__ B,
    u64*         __restrict__ stage)
{
    __shared__ int base_s[NB];
    __shared__ int cnt_s[NB];
    __shared__ int pre_s[NB];
    __shared__ int tsum[1024];
    const int t = threadIdx.x, c = blockIdx.x;

    // phase A: bucket total S and my column prefix P (chunks < c); one b/thread
    int S = 0, P = 0;
    if (t < NB) {
        #pragma unroll 8
        for (int cc = 0; cc < NC; ++cc) {
            int g = G[cc * NB + t];
            S += g;
            if (cc < c) P += g;
        }
        pre_s[t] = P;
    }
    tsum[t] = S;
    __syncthreads();

    // phase B: exclusive scan of the 1024 (>=NB) bucket totals
    for (int d = 1; d < 1024; d <<= 1) {
        int v = (t >= d) ? tsum[t - d] : 0;
        __syncthreads();
        tsum[t] += v;
        __syncthreads();
    }
    if (t < NB) base_s[t] = tsum[t] - S;       // exclusive bucket start
    __syncthreads();

    if (c == 0) {                               // publish B for bucket_csr
        if (t < NB) B[t] = base_s[t];
        if (t == 0) B[NB] = NE;
    }
    if (t < NB) {
        base_s[t] += pre_s[t];
        cnt_s[t] = 0;
    }
    __syncthreads();

    // phase C: scatter my chunk (16 waves -> latency hidden)
    int e0 = c * CHUNK;
    for (int i = t; i < CHUNK; i += 1024) {
        int e  = e0 + i;
        int d  = dst[e];
        int bk = d >> BSH;
        int r  = atomicAdd(&cnt_s[bk], 1);
        stage[base_s[bk] + r] = pack_edge(src[e], d & 63, ew[e]);
    }
}

// per bucket: counting sort by node, contiguous writeback, per-node offsets.
__global__ __launch_bounds__(256) void bucket_csr(
    const int* __restrict__ B, u64* __restrict__ stage, int* __restrict__ off)
{
    __shared__ u64 buf[BCAP];           // 32 KB
    __shared__ int cnt[64];
    __shared__ int cur[64];
    __shared__ int noff[64];
    int t = threadIdx.x, b = blockIdx.x;
    int e0 = B[b], e1 = B[b + 1];
    int n = e1 - e0;
    if (n > BCAP) n = BCAP;
    if (t < 64) { cnt[t] = 0; cur[t] = 0; }
    __syncthreads();
    for (int i = t; i < n; i += 256)
        atomicAdd(&cnt[(int)((stage[e0 + i] >> 17) & 63)], 1);
    __syncthreads();
    if (t == 0) {
        int run = 0;
        for (int j = 0; j < 64; ++j) { noff[j] = run; run += cnt[j]; }
    }
    __syncthreads();
    int n0 = b << BSH;
    if (t < 64 && (n0 + t) < NN) off[n0 + t] = e0 + noff[t];
    if (b == NB - 1 && t == 0) off[NN] = NE;
    for (int i = t; i < n; i += 256) {
        u64 p = stage[e0 + i];
        int d6 = (int)((p >> 17) & 63);
        int r = atomicAdd(&cur[d6], 1);
        buf[noff[d6] + r] = p;
    }
    __syncthreads();
    for (int i = t; i < n; i += 256) stage[e0 + i] = buf[i];
}

// ---- per-layer aggregate: 16 lanes/node x 16B loads (8 bf16), 8-deep ------

__global__ __launch_bounds__(256) void aggregate(
    const ushort* __restrict__ hb,
    const int*    __restrict__ off,
    const u64*    __restrict__ epk,
    const float*  __restrict__ We,
    const float*  __restrict__ be,
    ushort*       __restrict__ aggb)
{
    int tid = blockIdx.x * 256 + threadIdx.x;
    int n = tid >> 4;
    if (n >= NN) return;
    int d8 = (tid & 15) << 3;

    float4 wv0 = *(const float4*)(We + d8);
    float4 wv1 = *(const float4*)(We + d8 + 4);
    float4 bv0 = *(const float4*)(be + d8);
    float4 bv1 = *(const float4*)(be + d8 + 4);

    int e0 = off[n], e1 = off[n + 1];
    float a0=0.f,a1=0.f,a2=0.f,a3=0.f,a4=0.f,a5=0.f,a6=0.f,a7=0.f;

    for (int e = e0; e < e1; e += 8) {
        int m = e1 - e; if (m > 8) m = 8;
        u64 p[8];
        #pragma unroll
        for (int k = 0; k < 8; ++k) p[k] = (k < m) ? epk[e + k] : 0;
        u32x4 hv[8];
        #pragma unroll
        for (int k = 0; k < 8; ++k)
            hv[k] = *(const u32x4*)(hb + (size_t)(p[k] & 0x1FFFF) * D + d8);
        #pragma unroll
        for (int k = 0; k < 8; ++k) {
            if (k < m) {
                float w = __uint_as_float((u32)(p[k] >> 32));
                a0 += fmaxf(0.f, bfl(hv[k].x) + fmaf(w, wv0.x, bv0.x));
                a1 += fmaxf(0.f, bfh(hv[k].x) + fmaf(w, wv0.y, bv0.y));
                a2 += fmaxf(0.f, bfl(hv[k].y) + fmaf(w, wv0.z, bv0.z));
                a3 += fmaxf(0.f, bfh(hv[k].y) + fmaf(w, wv0.w, bv0.w));
                a4 += fmaxf(0.f, bfl(hv[k].z) + fmaf(w, wv1.x, bv1.x));
                a5 += fmaxf(0.f, bfh(hv[k].z) + fmaf(w, wv1.y, bv1.y));
                a6 += fmaxf(0.f, bfl(hv[k].w) + fmaf(w, wv1.z, bv1.z));
                a7 += fmaxf(0.f, bfh(hv[k].w) + fmaf(w, wv1.w, bv1.w));
            }
        }
    }
    u32x4 o;
    o.x = (u32)f2bf(a0) | ((u32)f2bf(a1) << 16);
    o.y = (u32)f2bf(a2) | ((u32)f2bf(a3) << 16);
    o.z = (u32)f2bf(a4) | ((u32)f2bf(a5) << 16);
    o.w = (u32)f2bf(a6) | ((u32)f2bf(a7) << 16);
    __builtin_nontemporal_store(o, (u32x4*)(aggb + (size_t)n * D + d8));
}

// ---------- MFMA GEMM: out = (relu?)((A1+A2) @ W + bias) ----------

__global__ __launch_bounds__(256) void gemm_mfma(
    const ushort* __restrict__ A1b,
    const ushort* __restrict__ A2b,   // aggb (streamed, read-once)
    const ushort* __restrict__ Wtb,
    const float*  __restrict__ bias,
    float*        __restrict__ outf,   // layer 2 (or null)
    ushort*       __restrict__ outb,   // layer 1 (or null)
    int relu)
{
    __shared__ ushort As[GR * 140];
    __shared__ ushort Ws[D * 140];

    const int t    = threadIdx.x;
    const int row0 = blockIdx.x * GR;

    for (int c = t; c < GR * (D / 4); c += 256) {
        int r  = c >> 5;
        int k4 = (c & 31) << 2;
        int row = row0 + r;
        uint2 o = make_uint2(0u, 0u);
        if (row < NN) {
            uint2 u1 = *(const uint2*)(A1b + (size_t)row * D + k4);
            u64 uu = __builtin_nontemporal_load((const u64*)(A2b + (size_t)row * D + k4));
            uint2 u2 = make_uint2((u32)uu, (u32)(uu >> 32));
            float s0 = bfl(u1.x) + bfl(u2.x);
            float s1 = bfh(u1.x) + bfh(u2.x);
            float s2 = bfl(u1.y) + bfl(u2.y);
            float s3 = bfh(u1.y) + bfh(u2.y);
            o.x = (u32)f2bf(s0) | ((u32)f2bf(s1) << 16);
            o.y = (u32)f2bf(s2) | ((u32)f2bf(s3) << 16);
        }
        *(uint2*)&As[r * 140 + k4] = o;
    }
    for (int c = t; c < D * (D / 4); c += 256) {
        int r  = c >> 5;
        int k4 = (c & 31) << 2;
        *(uint2*)&Ws[r * 140 + k4] = *(const uint2*)(Wtb + r * D + k4);
    }
    __syncthreads();

    const int wave = t >> 6;
    const int lane = t & 63;
    const int q    = lane >> 4;
    const int m    = lane & 15;
    const int wr   = (wave >> 1) * 32;
    const int wc   = (wave & 1) * 64;

    f32x4 acc[2][4] = {};
    #pragma unroll
    for (int kb = 0; kb < 4; ++kb) {
        int ak = kb * 32 + q * 8;
        short8 af[2];
        #pragma unroll
        for (int rg = 0; rg < 2; ++rg)
            af[rg] = *(const short8*)&As[(wr + rg * 16 + m) * 140 + ak];
        #pragma unroll
        for (int ct = 0; ct < 4; ++ct) {
            short8 bf = *(const short8*)&Ws[(wc + ct * 16 + m) * 140 + ak];
            #pragma unroll
            for (int rg = 0; rg < 2; ++rg)
                acc[rg][ct] = __builtin_amdgcn_mfma_f32_16x16x32_bf16(
                    af[rg], bf, acc[rg][ct], 0, 0, 0);
        }
    }

    #pragma unroll
    for (int ct = 0; ct < 4; ++ct) {
        int col = wc + ct * 16 + m;
        float bc = bias[col];
        #pragma unroll
        for (int rg = 0; rg < 2; ++rg) {
            #pragma unroll
            for (int r = 0; r < 4; ++r) {
                int grow = row0 + wr + rg * 16 + q * 4 + r;
                if (grow < NN) {
                    float v = acc[rg][ct][r] + bc;
                    if (relu) v = fmaxf(0.f, v);
                    if (outb) outb[(size_t)grow * D + col] = f2bf(v);
                    else __builtin_nontemporal_store(v, outf + (size_t)grow * D + col);
                }
            }
        }
    }
}

extern "C" void kernel_launch(void* const* d_in, const int* in_sizes, int n_in,
                              void* d_out, int out_size, void* d_ws, size_t ws_size,
                              hipStream_t stream)
{
    const float* x   = (const float*)d_in[0];
    const int*   ei  = (const int*)  d_in[1];
    const float* ew  = (const float*)d_in[2];
    const float* We1 = (const float*)d_in[3];
    const float* be1 = (const float*)d_in[4];
    const float* W1  = (const float*)d_in[5];
    const float* b1  = (const float*)d_in[6];
    const float* We2 = (const float*)d_in[7];
    const float* be2 = (const float*)d_in[8];
    const float* W2  = (const float*)d_in[9];
    const float* b2  = (const float*)d_in[10];

    float* out = (float*)d_out;

    // workspace (~46 MB)
    ushort* xb   = (ushort*)d_ws;                    // NN*D bf16
    ushort* hb   = xb + (size_t)NN * D;              // NN*D
    ushort* aggb = hb + (size_t)NN * D;              // NN*D
    ushort* Wt1  = aggb + (size_t)NN * D;            // 16384
    ushort* Wt2  = Wt1 + D * D;                      // 16384
    u64*   stage = (u64*)(Wt2 + D * D);              // NE u64
    int*   G     = (int*)(stage + NE);               // NC*NB
    int*   B     = G + NC * NB;                      // NB+1
    int*   off   = B + NB + 2;                       // NN+1

    const int* src = ei;
    const int* dst = ei + NE;

    dim3 agrid((NN * 16 + 255) / 256);               // 3125

    // ---- prep (cast x, transpose W) + hist, one launch ----
    prep_hist<<<CBLK + 8 + NC, 256, 0, stream>>>(x, xb, W1, W2, Wt1, Wt2,
                                                 dst, G);

    // ---- bucket-sorted CSR build (scan folded into scatter) ----
    bucket_scatter<<<NC, 1024, 0, stream>>>(src, dst, ew, G, B, stage);
    bucket_csr<<<NB, 256, 0, stream>>>(B, stage, off);

    // ---- layer 1 ----
    aggregate<<<agrid, 256, 0, stream>>>(xb, off, stage, We1, be1, aggb);
    gemm_mfma<<<GG, 256, 0, stream>>>(xb, aggb, Wt1, b1, nullptr, hb, 1);

    // ---- layer 2 ----
    aggregate<<<agrid, 256, 0, stream>>>(hb, off, stage, We2, be2, aggb);
    gemm_mfma<<<GG, 256, 0, stream>>>(hb, aggb, Wt2, b2, out, nullptr, 0);
}